// Round 13
// baseline (106.085 us; speedup 1.0000x reference)
//
#include <hip/hip_runtime.h>

typedef _Float16 f16;
typedef _Float16 f16x4 __attribute__((ext_vector_type(4)));
typedef _Float16 f16x8 __attribute__((ext_vector_type(8)));
typedef __fp16 fp16x2 __attribute__((ext_vector_type(2)));   // cvt_pkrtz native type
typedef float f32x4 __attribute__((ext_vector_type(4)));

#define MFMA_16x16x32_F16(A, B, C) __builtin_amdgcn_mfma_f32_16x16x32_f16((A), (B), (C), 0, 0, 0)

typedef const __attribute__((address_space(1))) char gchar;
typedef __attribute__((address_space(3))) char lchar;

__device__ __forceinline__ float fexp2(float x) { return __builtin_amdgcn_exp2f(x); }
__device__ __forceinline__ int swzb(int b) { return b ^ ((b >> 3) & 0x70); }  // involution, 8KB-tile-local

namespace {
constexpr int SB = 4096;                       // tokens per flattened batch = 64 tiles of 64
constexpr size_t BB = (size_t)SB * 64 * 2;     // f16 bytes per batch per tensor = 512KB
}

// V-ONLY token permutation within each 64-token tile (K stays identity!):
//   V^T stored slot n holds token kappa_V(n), kappa_V(32kt+8g+4a+v)=32kt+16a+4g+v.
//   Then PV's B-fragment slot 32kt+8g+j needs token 16(2kt+a)+4g+v — exactly the
//   lane's own QK^T output e[8kt+j], so P never touches LDS.
__device__ __forceinline__ int kinv(int r) {
    return 32 * (r >> 5) + 8 * ((r >> 2) & 3) + 4 * ((r >> 4) & 1) + (r & 3);
}

// ---------------- pre-pass: gather + fp16 convert + V tile-transpose ----------------
// Stores PRE-SWIZZLED within each 8KB tile; V additionally kappa_V-permuted in token axis.
__global__ __launch_bounds__(256)
void hilbert_prepass_kernel(const float* __restrict__ kp, const float* __restrict__ vp,
                            const int* __restrict__ perm,
                            char* __restrict__ kw, char* __restrict__ vtw)
{
    const int bid = blockIdx.x;
    const int batch = bid & 7;
    const int tile = bid >> 3;
    const int tid = (int)threadIdx.x;
    const int r = tid >> 2;       // token in tile
    const int c4 = tid & 3;       // 16-dim quarter

    __shared__ float Vl[64][68];  // fp32 V tile, padded

    const int t = tile * 64 + r;
    const int srow = perm[batch * 512 + (t >> 3)];
    const size_t boff = (size_t)srow * 512 + (t & 7) * 64 + c4 * 16;

    {   // K -> fp16, IDENTITY row placement, swizzled store
        const float* ks = kp + boff;
        const float4 k0 = *(const float4*)(ks + 0);
        const float4 k1 = *(const float4*)(ks + 4);
        const float4 k2 = *(const float4*)(ks + 8);
        const float4 k3 = *(const float4*)(ks + 12);
        f16x8 h0, h1;
        h0[0] = (f16)k0.x; h0[1] = (f16)k0.y; h0[2] = (f16)k0.z; h0[3] = (f16)k0.w;
        h0[4] = (f16)k1.x; h0[5] = (f16)k1.y; h0[6] = (f16)k1.z; h0[7] = (f16)k1.w;
        h1[0] = (f16)k2.x; h1[1] = (f16)k2.y; h1[2] = (f16)k2.z; h1[3] = (f16)k2.w;
        h1[4] = (f16)k3.x; h1[5] = (f16)k3.y; h1[6] = (f16)k3.z; h1[7] = (f16)k3.w;
        char* kt = kw + (size_t)batch * BB + (size_t)tile * 8192;
        const int o = r * 128 + c4 * 32;
        *(f16x8*)(kt + swzb(o)) = h0;
        *(f16x8*)(kt + swzb(o + 16)) = h1;
    }
    {   // V fp32 -> LDS
        const float* vs = vp + boff;
        *(float4*)&Vl[r][c4 * 16 + 0]  = *(const float4*)(vs + 0);
        *(float4*)&Vl[r][c4 * 16 + 4]  = *(const float4*)(vs + 4);
        *(float4*)&Vl[r][c4 * 16 + 8]  = *(const float4*)(vs + 8);
        *(float4*)&Vl[r][c4 * 16 + 12] = *(const float4*)(vs + 12);
    }
    __syncthreads();
    {   // transpose out of LDS: thread owns dim d, tokens 16a..16a+15; kappa_V cols
        const int d = tid >> 2;
        const int a = tid & 3;
        char* vt = vtw + (size_t)batch * BB + (size_t)tile * 8192;
        const int b0 = 32 * (a >> 1) + 4 * (a & 1);
#pragma unroll
        for (int gp = 0; gp < 4; ++gp) {
            f16x4 qv;
#pragma unroll
            for (int v = 0; v < 4; ++v) qv[v] = (f16)Vl[16 * a + 4 * gp + v][d];
            *(f16x4*)(vt + swzb(d * 128 + (b0 + 8 * gp) * 2)) = qv;
        }
    }
}

// ---------------- main attention ----------------
// 256 blocks (1/CU) x 1024 threads = 16 waves = 4 waves/SIMD.
// Wave = (wq, q): q-slot wq owns 32 q-rows; KV-quarter q handles tiles {4*it+q},
// it=0..15. NO-MAX softmax; P in registers (V-kappa layout).
// T4 counted-vmcnt pipeline: K-stage(next) -> QK -> V-stage(next) -> softmax ->
// [vmcnt(2)+s_barrier: prev V confirmed, K(next) stays IN FLIGHT] -> PV ->
// [vmcnt(2)+s_barrier: K(next) confirmed, V(next) stays in flight].
// NO vmcnt(0) drain inside the loop (the m97/m233 stall this round removes).
// LDS (128KB): two 64KB buffers {4 K-tiles | 4 Vt-tiles}; epilogue reuses as merge.
__global__ __launch_bounds__(1024, 4)
void hilbert_attn_kernel(const float* __restrict__ qp,
                         const int* __restrict__ perm,
                         const char* __restrict__ kw, const char* __restrict__ vtw,
                         float* __restrict__ op)
{
    __shared__ __align__(16) char SM[131072];

    const int bid = blockIdx.x;
    const int batch = bid & 7;            // XCD-affine: one batch per XCD
    const int qbase = (bid >> 3) * 128;
    const int tid = (int)threadIdx.x;
    const int w = tid >> 6;
    const int lane = tid & 63;
    const int l16 = lane & 15;
    const int g = lane >> 4;
    const int q = w >> 2;                 // KV quarter
    const int wq = w & 3;                 // q-slot
    const int swz = (l16 & 7) << 4;

    // Q B-fragments for both 16-row slots; scale*log2e folded
    f16x8 Qf0[2], Qf1[2];
    {
        constexpr float qscl = 0.125f * 1.44269504088896340736f;
#pragma unroll
        for (int s = 0; s < 2; ++s) {
            const int t = qbase + wq * 32 + s * 16 + l16;
            const int srow = perm[batch * 512 + (t >> 3)];
            const float* src = qp + (size_t)srow * 512 + (t & 7) * 64 + g * 8;
#pragma unroll
            for (int kt = 0; kt < 2; ++kt) {
                const float4 x0 = *(const float4*)(src + 32 * kt);
                const float4 x1 = *(const float4*)(src + 32 * kt + 4);
                f16x8 f;
                f[0] = (f16)(x0.x * qscl); f[1] = (f16)(x0.y * qscl);
                f[2] = (f16)(x0.z * qscl); f[3] = (f16)(x0.w * qscl);
                f[4] = (f16)(x1.x * qscl); f[5] = (f16)(x1.y * qscl);
                f[6] = (f16)(x1.z * qscl); f[7] = (f16)(x1.w * qscl);
                if (s == 0) Qf0[kt] = f; else Qf1[kt] = f;
            }
        }
    }

    f32x4 oacc0[4], oacc1[4];
#pragma unroll
    for (int i = 0; i < 4; ++i) {
        oacc0[i] = (f32x4){0.f, 0.f, 0.f, 0.f};
        oacc1[i] = (f32x4){0.f, 0.f, 0.f, 0.f};
    }
    float lr0 = 0.f, lr1 = 0.f;

    const char* ksrc = kw + (size_t)batch * BB + (size_t)tid * 16;
    const char* vsrc = vtw + (size_t)batch * BB + (size_t)tid * 16;

    {   // prologue: stage tile-quad 0 (4 K + 4 V = 64KB) into buffer 0, full drain once
        lchar* dst = (lchar*)&SM[w << 10];
        __builtin_amdgcn_global_load_lds((gchar*)(ksrc), dst, 16, 0, 0);
        __builtin_amdgcn_global_load_lds((gchar*)(ksrc + 16384), dst + 16384, 16, 0, 0);
        __builtin_amdgcn_global_load_lds((gchar*)(vsrc), dst + 32768, 16, 0, 0);
        __builtin_amdgcn_global_load_lds((gchar*)(vsrc + 16384), dst + 49152, 16, 0, 0);
    }
    asm volatile("s_waitcnt vmcnt(0)" ::: "memory");
    __builtin_amdgcn_s_barrier();

#pragma unroll 2
    for (int it = 0; it < 16; ++it) {        // 16 iters x 4 tiles = 64 tiles = all keys
        const int cur = it & 1;
        const int kbb = cur * 65536 + q * 8192;
        const int vbb = cur * 65536 + 32768 + q * 8192;
        const size_t go = (size_t)(it + 1) * 32768;
        lchar* dstb = (lchar*)&SM[(cur ^ 1) * 65536 + (w << 10)];

        if (it < 15) {   // issue K-stage for next buffer (stays in flight across end barrier)
            __builtin_amdgcn_global_load_lds((gchar*)(ksrc + go), dstb, 16, 0, 0);
            __builtin_amdgcn_global_load_lds((gchar*)(ksrc + go + 16384), dstb + 16384, 16, 0, 0);
        }

        // ---- S^T = K * Q^T for both q-slots, K fragments read ONCE ----
        f32x4 sa0[4], sa1[4];
#pragma unroll
        for (int i = 0; i < 4; ++i) {
            sa0[i] = (f32x4){0.f, 0.f, 0.f, 0.f};
            sa1[i] = (f32x4){0.f, 0.f, 0.f, 0.f};
        }
        __builtin_amdgcn_s_setprio(1);
#pragma unroll
        for (int kt = 0; kt < 2; ++kt) {
#pragma unroll
            for (int mt = 0; mt < 4; ++mt) {
                const int off = kbb + (l16 + 16 * mt) * 128 + (((g + 4 * kt) * 16) ^ swz);
                const f16x8 kf = *(const f16x8*)&SM[off];
                sa0[mt] = MFMA_16x16x32_F16(kf, Qf0[kt], sa0[mt]);
                sa1[mt] = MFMA_16x16x32_F16(kf, Qf1[kt], sa1[mt]);
            }
        }
        __builtin_amdgcn_s_setprio(0);

        if (it < 15) {   // issue V-stage for next buffer (confirmed at NEXT iter's mid barrier)
            __builtin_amdgcn_global_load_lds((gchar*)(vsrc + go), dstb + 32768, 16, 0, 0);
            __builtin_amdgcn_global_load_lds((gchar*)(vsrc + go + 16384), dstb + 49152, 16, 0, 0);
        }

        // ---- no-max softmax, P stays in registers (V-kappa layout) ----
        float e0[16], e1[16];
#pragma unroll
        for (int mt = 0; mt < 4; ++mt) {
#pragma unroll
            for (int v = 0; v < 4; ++v) {
                e0[4 * mt + v] = fexp2(sa0[mt][v]);
                e1[4 * mt + v] = fexp2(sa1[mt][v]);
            }
        }
#pragma unroll
        for (int i = 0; i < 16; ++i) { lr0 += e0[i]; lr1 += e1[i]; }

        union U8 { f16x8 v; fp16x2 h[4]; };
        U8 p0k0, p0k1, p1k0, p1k1;
#pragma unroll
        for (int i = 0; i < 4; ++i) {
            p0k0.h[i] = __builtin_amdgcn_cvt_pkrtz(e0[2 * i], e0[2 * i + 1]);
            p0k1.h[i] = __builtin_amdgcn_cvt_pkrtz(e0[8 + 2 * i], e0[9 + 2 * i]);
            p1k0.h[i] = __builtin_amdgcn_cvt_pkrtz(e1[2 * i], e1[2 * i + 1]);
            p1k1.h[i] = __builtin_amdgcn_cvt_pkrtz(e1[8 + 2 * i], e1[9 + 2 * i]);
        }

        // ---- mid barrier: this iter's V (staged last iter) confirmed; K(next) in flight ----
        // outstanding at this point: [V(cur) 2 loads (oldest, issued it-1)] + [K(next) 2 loads]
        if (it > 0) {
            if (it < 15) { asm volatile("s_waitcnt vmcnt(2)" ::: "memory"); }
            else         { asm volatile("s_waitcnt vmcnt(0)" ::: "memory"); }
            __builtin_amdgcn_s_barrier();
        }

        // ---- O^T += V^T * P^T, V fragments read ONCE for both slots ----
        __builtin_amdgcn_s_setprio(1);
#pragma unroll
        for (int kt = 0; kt < 2; ++kt) {
            const f16x8 pf0 = kt ? p0k1.v : p0k0.v;
            const f16x8 pf1 = kt ? p1k1.v : p1k0.v;
#pragma unroll
            for (int mtd = 0; mtd < 4; ++mtd) {
                const int voff = vbb + (l16 + 16 * mtd) * 128 + (((g + 4 * kt) * 16) ^ swz);
                const f16x8 vf = *(const f16x8*)&SM[voff];
                oacc0[mtd] = MFMA_16x16x32_F16(vf, pf0, oacc0[mtd]);
                oacc1[mtd] = MFMA_16x16x32_F16(vf, pf1, oacc1[mtd]);
            }
        }
        __builtin_amdgcn_s_setprio(0);

        // ---- end barrier: K(next) confirmed for next iter's QK; V(next) stays in flight ----
        if (it < 15) {
            asm volatile("s_waitcnt vmcnt(2)" ::: "memory");
            __builtin_amdgcn_s_barrier();
        }
    }

    // ---- reduce l across the 4 key-groups of each wave ----
    lr0 += __shfl_xor(lr0, 16);
    lr0 += __shfl_xor(lr0, 32);
    lr1 += __shfl_xor(lr1, 16);
    lr1 += __shfl_xor(lr1, 32);

    __syncthreads();   // loop done (vmcnt already 0 at it=15 mid); reuse SM for merge

    // ---- merge across 4 KV-quarters: q=1,2,3 dump partials, q=0 combines ----
    float* OB = (float*)SM;                 // 12 waves x 8KB (32 rows x 64 dims)
    float* ML = (float*)&SM[98304];         // 12 waves x 32 l-values
    if (q >= 1) {
        float* ob = OB + ((q - 1) * 4 + wq) * 2048;
#pragma unroll
        for (int mtd = 0; mtd < 4; ++mtd) {
            *(f32x4*)&ob[l16 * 64 + mtd * 16 + g * 4] = oacc0[mtd];
            *(f32x4*)&ob[(16 + l16) * 64 + mtd * 16 + g * 4] = oacc1[mtd];
        }
        if (g == 0) {
            ML[((q - 1) * 4 + wq) * 32 + l16] = lr0;
            ML[((q - 1) * 4 + wq) * 32 + 16 + l16] = lr1;
        }
    }
    __syncthreads();
    if (q == 0) {
#pragma unroll
        for (int s = 0; s < 2; ++s) {
            float lsum = (s == 0) ? lr0 : lr1;
#pragma unroll
            for (int p = 0; p < 3; ++p) lsum += ML[(p * 4 + wq) * 32 + s * 16 + l16];
            const float linv = 1.f / lsum;
            const int t = qbase + wq * 32 + s * 16 + l16;
            const int srow = perm[t];       // scatter uses FULL-t perm (round-1 lesson)
            float* dst = op + (size_t)srow * 512 + batch * 64 + 4 * g;
#pragma unroll
            for (int mtd = 0; mtd < 4; ++mtd) {
                f32x4 acc = (s == 0) ? oacc0[mtd] : oacc1[mtd];
#pragma unroll
                for (int p = 0; p < 3; ++p) {
                    const f32x4 o2 = *(const f32x4*)&OB[(p * 4 + wq) * 2048 +
                                                        (s * 16 + l16) * 64 + mtd * 16 + g * 4];
                    acc[0] += o2[0]; acc[1] += o2[1]; acc[2] += o2[2]; acc[3] += o2[3];
                }
                float4 o;
                o.x = acc[0] * linv; o.y = acc[1] * linv;
                o.z = acc[2] * linv; o.w = acc[3] * linv;
                *(float4*)(dst + 16 * mtd) = o;
            }
        }
    }
}

extern "C" void kernel_launch(void* const* d_in, const int* in_sizes, int n_in,
                              void* d_out, int out_size, void* d_ws, size_t ws_size,
                              hipStream_t stream) {
    (void)in_sizes; (void)n_in; (void)out_size; (void)ws_size;
    const float* q = (const float*)d_in[0];
    const float* k = (const float*)d_in[1];
    const float* v = (const float*)d_in[2];
    const int* perm = (const int*)d_in[3];
    float* out = (float*)d_out;
    char* kw = (char*)d_ws;          // 4MB
    char* vtw = kw + 8 * BB;         // 4MB
    hipLaunchKernelGGL(hilbert_prepass_kernel, dim3(512), dim3(256), 0, stream,
                       k, v, perm, kw, vtw);
    hipLaunchKernelGGL(hilbert_attn_kernel, dim3(256), dim3(1024), 0, stream,
                       q, perm, kw, vtw, out);
}

// Round 14
// 50.721 us; speedup vs baseline: 2.0916x; 2.0916x over previous
//
#include <hip/hip_runtime.h>

typedef _Float16 f16;
typedef _Float16 f16x4 __attribute__((ext_vector_type(4)));
typedef _Float16 f16x8 __attribute__((ext_vector_type(8)));
typedef __fp16 fp16x2 __attribute__((ext_vector_type(2)));   // cvt_pkrtz native type
typedef float f32x4 __attribute__((ext_vector_type(4)));

#define MFMA_16x16x32_F16(A, B, C) __builtin_amdgcn_mfma_f32_16x16x32_f16((A), (B), (C), 0, 0, 0)

typedef const __attribute__((address_space(1))) char gchar;
typedef __attribute__((address_space(3))) char lchar;

__device__ __forceinline__ float fexp2(float x) { return __builtin_amdgcn_exp2f(x); }
__device__ __forceinline__ int swzb(int b) { return b ^ ((b >> 3) & 0x70); }  // involution, 8KB-tile-local

namespace {
constexpr int SB = 4096;                       // tokens per flattened batch = 64 tiles of 64
constexpr size_t BB = (size_t)SB * 64 * 2;     // f16 bytes per batch per tensor = 512KB
}

// V-ONLY token permutation within each 64-token tile (K stays identity!):
//   V^T stored slot n holds token kappa_V(n), kappa_V(32kt+8g+4a+v)=32kt+16a+4g+v.
//   PV's B-fragment slot 32kt+8g+j then needs exactly the lane's own QK^T output
//   e[8kt+j], so P never touches LDS.
__device__ __forceinline__ int kinv(int r) {
    return 32 * (r >> 5) + 8 * ((r >> 2) & 3) + 4 * ((r >> 4) & 1) + (r & 3);
}

// ---------------- pre-pass: gather + fp16 convert + V tile-transpose ----------------
// Stores PRE-SWIZZLED within each 8KB tile; V additionally kappa_V-permuted in token axis.
__global__ __launch_bounds__(256)
void hilbert_prepass_kernel(const float* __restrict__ kp, const float* __restrict__ vp,
                            const int* __restrict__ perm,
                            char* __restrict__ kw, char* __restrict__ vtw)
{
    const int bid = blockIdx.x;
    const int batch = bid & 7;
    const int tile = bid >> 3;
    const int tid = (int)threadIdx.x;
    const int r = tid >> 2;       // token in tile
    const int c4 = tid & 3;       // 16-dim quarter

    __shared__ float Vl[64][68];  // fp32 V tile, padded

    const int t = tile * 64 + r;
    const int srow = perm[batch * 512 + (t >> 3)];
    const size_t boff = (size_t)srow * 512 + (t & 7) * 64 + c4 * 16;

    {   // K -> fp16, IDENTITY row placement, swizzled store
        const float* ks = kp + boff;
        const float4 k0 = *(const float4*)(ks + 0);
        const float4 k1 = *(const float4*)(ks + 4);
        const float4 k2 = *(const float4*)(ks + 8);
        const float4 k3 = *(const float4*)(ks + 12);
        f16x8 h0, h1;
        h0[0] = (f16)k0.x; h0[1] = (f16)k0.y; h0[2] = (f16)k0.z; h0[3] = (f16)k0.w;
        h0[4] = (f16)k1.x; h0[5] = (f16)k1.y; h0[6] = (f16)k1.z; h0[7] = (f16)k1.w;
        h1[0] = (f16)k2.x; h1[1] = (f16)k2.y; h1[2] = (f16)k2.z; h1[3] = (f16)k2.w;
        h1[4] = (f16)k3.x; h1[5] = (f16)k3.y; h1[6] = (f16)k3.z; h1[7] = (f16)k3.w;
        char* kt = kw + (size_t)batch * BB + (size_t)tile * 8192;
        const int o = r * 128 + c4 * 32;
        *(f16x8*)(kt + swzb(o)) = h0;
        *(f16x8*)(kt + swzb(o + 16)) = h1;
    }
    {   // V fp32 -> LDS
        const float* vs = vp + boff;
        *(float4*)&Vl[r][c4 * 16 + 0]  = *(const float4*)(vs + 0);
        *(float4*)&Vl[r][c4 * 16 + 4]  = *(const float4*)(vs + 4);
        *(float4*)&Vl[r][c4 * 16 + 8]  = *(const float4*)(vs + 8);
        *(float4*)&Vl[r][c4 * 16 + 12] = *(const float4*)(vs + 12);
    }
    __syncthreads();
    {   // transpose out of LDS: thread owns dim d, tokens 16a..16a+15; kappa_V cols
        const int d = tid >> 2;
        const int a = tid & 3;
        char* vt = vtw + (size_t)batch * BB + (size_t)tile * 8192;
        const int b0 = 32 * (a >> 1) + 4 * (a & 1);
#pragma unroll
        for (int gp = 0; gp < 4; ++gp) {
            f16x4 qv;
#pragma unroll
            for (int v = 0; v < 4; ++v) qv[v] = (f16)Vl[16 * a + 4 * gp + v][d];
            *(f16x4*)(vt + swzb(d * 128 + (b0 + 8 * gp) * 2)) = qv;
        }
    }
}

// ---------------- main attention ----------------
// 256 blocks (1/CU) x 512 threads = 8 waves (r9 geometry: VGPR-safe at 256 budget).
// Wave = (wq, half): q-slot wq owns 32 q-rows (two 16-row subtiles sharing every
// K/V fragment read); half splits KV tiles even/odd. NO-MAX softmax; P in regs.
// T4 counted-vmcnt pipeline (never vmcnt(0) in-loop):
//   issue Kn(2) -> QK -> issue Vn(2) -> softmax -> [vmcnt(4)+s_barrier: Vcur
//   confirmed, Kn/Vn IN FLIGHT] -> PV -> [vmcnt(2)+s_barrier: Kn confirmed,
//   Vn in flight]. Tail iteration peeled with vmcnt(0).
// LDS (64KB): two 32KB buffers {2 K-tiles | 2 Vt-tiles}; epilogue reuses as merge.
__global__ __launch_bounds__(512, 2)
void hilbert_attn_kernel(const float* __restrict__ qp,
                         const int* __restrict__ perm,
                         const char* __restrict__ kw, const char* __restrict__ vtw,
                         float* __restrict__ op)
{
    __shared__ __align__(16) char SM[65536];

    const int bid = blockIdx.x;
    const int batch = bid & 7;            // XCD-affine: one batch per XCD
    const int qbase = (bid >> 3) * 128;
    const int tid = (int)threadIdx.x;
    const int w = tid >> 6;
    const int lane = tid & 63;
    const int l16 = lane & 15;
    const int g = lane >> 4;
    const int half = w >> 2;
    const int wq = w & 3;
    const int swz = (l16 & 7) << 4;

    // Q B-fragments for both 16-row slots; scale*log2e folded
    f16x8 Qf0[2], Qf1[2];
    {
        constexpr float qscl = 0.125f * 1.44269504088896340736f;
#pragma unroll
        for (int s = 0; s < 2; ++s) {
            const int t = qbase + wq * 32 + s * 16 + l16;
            const int srow = perm[batch * 512 + (t >> 3)];
            const float* src = qp + (size_t)srow * 512 + (t & 7) * 64 + g * 8;
#pragma unroll
            for (int kt = 0; kt < 2; ++kt) {
                const float4 x0 = *(const float4*)(src + 32 * kt);
                const float4 x1 = *(const float4*)(src + 32 * kt + 4);
                f16x8 f;
                f[0] = (f16)(x0.x * qscl); f[1] = (f16)(x0.y * qscl);
                f[2] = (f16)(x0.z * qscl); f[3] = (f16)(x0.w * qscl);
                f[4] = (f16)(x1.x * qscl); f[5] = (f16)(x1.y * qscl);
                f[6] = (f16)(x1.z * qscl); f[7] = (f16)(x1.w * qscl);
                if (s == 0) Qf0[kt] = f; else Qf1[kt] = f;
            }
        }
    }

    f32x4 oacc0[4], oacc1[4];
#pragma unroll
    for (int i = 0; i < 4; ++i) {
        oacc0[i] = (f32x4){0.f, 0.f, 0.f, 0.f};
        oacc1[i] = (f32x4){0.f, 0.f, 0.f, 0.f};
    }
    float lr0 = 0.f, lr1 = 0.f;

    const char* ksrc = kw + (size_t)batch * BB + (size_t)tid * 16;
    const char* vsrc = vtw + (size_t)batch * BB + (size_t)tid * 16;

    union U8 { f16x8 v; fp16x2 h[4]; };

    {   // prologue: stage tile-pair 0 (2K + 2V = 32KB) into buffer 0, drain once
        lchar* dst = (lchar*)&SM[w << 10];
        __builtin_amdgcn_global_load_lds((gchar*)(ksrc), dst, 16, 0, 0);
        __builtin_amdgcn_global_load_lds((gchar*)(ksrc + 8192), dst + 8192, 16, 0, 0);
        __builtin_amdgcn_global_load_lds((gchar*)(vsrc), dst + 16384, 16, 0, 0);
        __builtin_amdgcn_global_load_lds((gchar*)(vsrc + 8192), dst + 24576, 16, 0, 0);
    }
    asm volatile("s_waitcnt vmcnt(0)" ::: "memory");
    __builtin_amdgcn_s_barrier();

    for (int it = 0; it < 31; ++it) {
        const int cur = it & 1;
        const int kbb = cur * 32768 + half * 8192;
        const int vbb = cur * 32768 + 16384 + half * 8192;
        const size_t go = (size_t)(it + 1) * 16384;
        lchar* dstb = (lchar*)&SM[(cur ^ 1) * 32768 + (w << 10)];

        // issue K(next) — stays in flight across the mid barrier
        __builtin_amdgcn_global_load_lds((gchar*)(ksrc + go), dstb, 16, 0, 0);
        __builtin_amdgcn_global_load_lds((gchar*)(ksrc + go + 8192), dstb + 8192, 16, 0, 0);

        // ---- S^T = K * Q^T for both q-slots, K fragments read ONCE ----
        f32x4 sa0[4], sa1[4];
#pragma unroll
        for (int i = 0; i < 4; ++i) {
            sa0[i] = (f32x4){0.f, 0.f, 0.f, 0.f};
            sa1[i] = (f32x4){0.f, 0.f, 0.f, 0.f};
        }
        __builtin_amdgcn_s_setprio(1);
#pragma unroll
        for (int kt = 0; kt < 2; ++kt) {
#pragma unroll
            for (int mt = 0; mt < 4; ++mt) {
                const int off = kbb + (l16 + 16 * mt) * 128 + (((g + 4 * kt) * 16) ^ swz);
                const f16x8 kf = *(const f16x8*)&SM[off];
                sa0[mt] = MFMA_16x16x32_F16(kf, Qf0[kt], sa0[mt]);
                sa1[mt] = MFMA_16x16x32_F16(kf, Qf1[kt], sa1[mt]);
            }
        }
        __builtin_amdgcn_s_setprio(0);

        // issue V(next) — confirmed at NEXT iter's mid barrier
        __builtin_amdgcn_global_load_lds((gchar*)(vsrc + go), dstb + 16384, 16, 0, 0);
        __builtin_amdgcn_global_load_lds((gchar*)(vsrc + go + 8192), dstb + 24576, 16, 0, 0);

        // ---- no-max softmax, P packed straight to registers (V-kappa layout) ----
        U8 p0k0, p0k1, p1k0, p1k1;
#pragma unroll
        for (int mt = 0; mt < 4; ++mt) {
            const float a0 = fexp2(sa0[mt][0]);
            const float a1 = fexp2(sa0[mt][1]);
            const float a2 = fexp2(sa0[mt][2]);
            const float a3 = fexp2(sa0[mt][3]);
            lr0 += (a0 + a1) + (a2 + a3);
            const float b0 = fexp2(sa1[mt][0]);
            const float b1 = fexp2(sa1[mt][1]);
            const float b2 = fexp2(sa1[mt][2]);
            const float b3 = fexp2(sa1[mt][3]);
            lr1 += (b0 + b1) + (b2 + b3);
            // e[4mt+v]; pack order: pXk0.h[i]=pack(e[2i],e[2i+1]), pXk1.h[i]=pack(e[8+2i],e[9+2i])
            if (mt < 2) {
                p0k0.h[2 * mt]     = __builtin_amdgcn_cvt_pkrtz(a0, a1);
                p0k0.h[2 * mt + 1] = __builtin_amdgcn_cvt_pkrtz(a2, a3);
                p1k0.h[2 * mt]     = __builtin_amdgcn_cvt_pkrtz(b0, b1);
                p1k0.h[2 * mt + 1] = __builtin_amdgcn_cvt_pkrtz(b2, b3);
            } else {
                p0k1.h[2 * (mt - 2)]     = __builtin_amdgcn_cvt_pkrtz(a0, a1);
                p0k1.h[2 * (mt - 2) + 1] = __builtin_amdgcn_cvt_pkrtz(a2, a3);
                p1k1.h[2 * (mt - 2)]     = __builtin_amdgcn_cvt_pkrtz(b0, b1);
                p1k1.h[2 * (mt - 2) + 1] = __builtin_amdgcn_cvt_pkrtz(b2, b3);
            }
        }

        // ---- mid barrier: V(cur) confirmed; K(next)/V(next) stay in flight ----
        // outstanding: [Vcur 2][Kn 2][Vn 2] = 6 -> wait to 4 drains Vcur only (it=0: 4, no-op)
        asm volatile("s_waitcnt vmcnt(4)" ::: "memory");
        __builtin_amdgcn_s_barrier();

        // ---- O^T += V^T * P^T, V fragments read ONCE for both slots ----
        __builtin_amdgcn_s_setprio(1);
#pragma unroll
        for (int kt = 0; kt < 2; ++kt) {
            const f16x8 pf0 = kt ? p0k1.v : p0k0.v;
            const f16x8 pf1 = kt ? p1k1.v : p1k0.v;
#pragma unroll
            for (int mtd = 0; mtd < 4; ++mtd) {
                const int voff = vbb + (l16 + 16 * mtd) * 128 + (((g + 4 * kt) * 16) ^ swz);
                const f16x8 vf = *(const f16x8*)&SM[voff];
                oacc0[mtd] = MFMA_16x16x32_F16(vf, pf0, oacc0[mtd]);
                oacc1[mtd] = MFMA_16x16x32_F16(vf, pf1, oacc1[mtd]);
            }
        }
        __builtin_amdgcn_s_setprio(0);

        // ---- end barrier: K(next) confirmed; V(next) stays in flight ----
        asm volatile("s_waitcnt vmcnt(2)" ::: "memory");
        __builtin_amdgcn_s_barrier();
    }

    {   // ---- tail iteration it=31 (buffer 1; outstanding at entry: [V31 2]) ----
        const int kbb = 32768 + half * 8192;
        const int vbb = 32768 + 16384 + half * 8192;

        f32x4 sa0[4], sa1[4];
#pragma unroll
        for (int i = 0; i < 4; ++i) {
            sa0[i] = (f32x4){0.f, 0.f, 0.f, 0.f};
            sa1[i] = (f32x4){0.f, 0.f, 0.f, 0.f};
        }
#pragma unroll
        for (int kt = 0; kt < 2; ++kt) {
#pragma unroll
            for (int mt = 0; mt < 4; ++mt) {
                const int off = kbb + (l16 + 16 * mt) * 128 + (((g + 4 * kt) * 16) ^ swz);
                const f16x8 kf = *(const f16x8*)&SM[off];
                sa0[mt] = MFMA_16x16x32_F16(kf, Qf0[kt], sa0[mt]);
                sa1[mt] = MFMA_16x16x32_F16(kf, Qf1[kt], sa1[mt]);
            }
        }
        U8 p0k0, p0k1, p1k0, p1k1;
#pragma unroll
        for (int mt = 0; mt < 4; ++mt) {
            const float a0 = fexp2(sa0[mt][0]);
            const float a1 = fexp2(sa0[mt][1]);
            const float a2 = fexp2(sa0[mt][2]);
            const float a3 = fexp2(sa0[mt][3]);
            lr0 += (a0 + a1) + (a2 + a3);
            const float b0 = fexp2(sa1[mt][0]);
            const float b1 = fexp2(sa1[mt][1]);
            const float b2 = fexp2(sa1[mt][2]);
            const float b3 = fexp2(sa1[mt][3]);
            lr1 += (b0 + b1) + (b2 + b3);
            if (mt < 2) {
                p0k0.h[2 * mt]     = __builtin_amdgcn_cvt_pkrtz(a0, a1);
                p0k0.h[2 * mt + 1] = __builtin_amdgcn_cvt_pkrtz(a2, a3);
                p1k0.h[2 * mt]     = __builtin_amdgcn_cvt_pkrtz(b0, b1);
                p1k0.h[2 * mt + 1] = __builtin_amdgcn_cvt_pkrtz(b2, b3);
            } else {
                p0k1.h[2 * (mt - 2)]     = __builtin_amdgcn_cvt_pkrtz(a0, a1);
                p0k1.h[2 * (mt - 2) + 1] = __builtin_amdgcn_cvt_pkrtz(a2, a3);
                p1k1.h[2 * (mt - 2)]     = __builtin_amdgcn_cvt_pkrtz(b0, b1);
                p1k1.h[2 * (mt - 2) + 1] = __builtin_amdgcn_cvt_pkrtz(b2, b3);
            }
        }
        asm volatile("s_waitcnt vmcnt(0)" ::: "memory");
        __builtin_amdgcn_s_barrier();
#pragma unroll
        for (int kt = 0; kt < 2; ++kt) {
            const f16x8 pf0 = kt ? p0k1.v : p0k0.v;
            const f16x8 pf1 = kt ? p1k1.v : p1k0.v;
#pragma unroll
            for (int mtd = 0; mtd < 4; ++mtd) {
                const int voff = vbb + (l16 + 16 * mtd) * 128 + (((g + 4 * kt) * 16) ^ swz);
                const f16x8 vf = *(const f16x8*)&SM[voff];
                oacc0[mtd] = MFMA_16x16x32_F16(vf, pf0, oacc0[mtd]);
                oacc1[mtd] = MFMA_16x16x32_F16(vf, pf1, oacc1[mtd]);
            }
        }
    }

    // ---- reduce l across the 4 key-groups of each wave ----
    lr0 += __shfl_xor(lr0, 16);
    lr0 += __shfl_xor(lr0, 32);
    lr1 += __shfl_xor(lr1, 16);
    lr1 += __shfl_xor(lr1, 32);

    __syncthreads();   // loop done; reuse SM for merge

    // ---- merge wave pairs (w, w+4): l = la+lb, O = Oa+Ob ----
    float* OB = (float*)SM;                 // 4 pairs x 8KB (32 rows x 64 dims)
    float* ML = (float*)&SM[32768];         // 4 pairs x 32 l-values
    if (w >= 4) {
        float* ob = OB + wq * 2048;
#pragma unroll
        for (int mtd = 0; mtd < 4; ++mtd) {
            *(f32x4*)&ob[l16 * 64 + mtd * 16 + g * 4] = oacc0[mtd];
            *(f32x4*)&ob[(16 + l16) * 64 + mtd * 16 + g * 4] = oacc1[mtd];
        }
        if (g == 0) {
            ML[wq * 32 + l16] = lr0;
            ML[wq * 32 + 16 + l16] = lr1;
        }
    }
    __syncthreads();
    if (w < 4) {
        float* ob = OB + wq * 2048;
#pragma unroll
        for (int s = 0; s < 2; ++s) {
            const float lmine = (s == 0) ? lr0 : lr1;
            const float linv = 1.f / (lmine + ML[wq * 32 + s * 16 + l16]);
            const int t = qbase + wq * 32 + s * 16 + l16;
            const int srow = perm[t];       // scatter uses FULL-t perm (round-1 lesson)
            float* dst = op + (size_t)srow * 512 + batch * 64 + 4 * g;
#pragma unroll
            for (int mtd = 0; mtd < 4; ++mtd) {
                const f32x4 mine = (s == 0) ? oacc0[mtd] : oacc1[mtd];
                const f32x4 o2 = *(const f32x4*)&ob[(s * 16 + l16) * 64 + mtd * 16 + g * 4];
                float4 o;
                o.x = (mine[0] + o2[0]) * linv;
                o.y = (mine[1] + o2[1]) * linv;
                o.z = (mine[2] + o2[2]) * linv;
                o.w = (mine[3] + o2[3]) * linv;
                *(float4*)(dst + 16 * mtd) = o;
            }
        }
    }
}

extern "C" void kernel_launch(void* const* d_in, const int* in_sizes, int n_in,
                              void* d_out, int out_size, void* d_ws, size_t ws_size,
                              hipStream_t stream) {
    (void)in_sizes; (void)n_in; (void)out_size; (void)ws_size;
    const float* q = (const float*)d_in[0];
    const float* k = (const float*)d_in[1];
    const float* v = (const float*)d_in[2];
    const int* perm = (const int*)d_in[3];
    float* out = (float*)d_out;
    char* kw = (char*)d_ws;          // 4MB
    char* vtw = kw + 8 * BB;         // 4MB
    hipLaunchKernelGGL(hilbert_prepass_kernel, dim3(512), dim3(256), 0, stream,
                       k, v, perm, kw, vtw);
    hipLaunchKernelGGL(hilbert_attn_kernel, dim3(256), dim3(512), 0, stream,
                       q, perm, kw, vtw, out);
}